// Round 4
// baseline (705.576 us; speedup 1.0000x reference)
//
#include <hip/hip_runtime.h>

typedef unsigned short u16;
typedef __attribute__((ext_vector_type(8))) short short8;
typedef __attribute__((ext_vector_type(4))) float f32x4;
typedef __attribute__((ext_vector_type(4))) unsigned int u32x4;

__device__ __forceinline__ u16 f2bf(float f) {
    unsigned int x = __float_as_uint(f);
    x += 0x7fff + ((x >> 16) & 1);   // RNE
    return (u16)(x >> 16);
}

union Cvt32 { u32x4 v[4]; u16 u[32]; };

// load 32 consecutive fp32 and convert to 32 bf16
__device__ __forceinline__ void ld32f_bf(const float* __restrict__ p, Cvt32& t) {
#pragma unroll
    for (int j = 0; j < 32; j += 4) {
        f32x4 x = *(const f32x4*)(p + j);
        t.u[j]     = f2bf(x[0]);
        t.u[j + 1] = f2bf(x[1]);
        t.u[j + 2] = f2bf(x[2]);
        t.u[j + 3] = f2bf(x[3]);
    }
}

// ---------------------------------------------------------------------------
// Build per-head transposed bf16 weights into d_out scratch (dead until the
// final GEMM):
//   wt[0      .. 131071] = WkvT: [h][n=0..63][k]  n<32: key_w, n>=32: value_w
//   wt[131072 .. 262143] = WqgT: [h][n=0..63][k]  n<32: query_w, n>=32: gating_w
// src weights are fp32 (k=256, h=8, c=32): flat k*256 + h*32 + c.
// ---------------------------------------------------------------------------
__global__ __launch_bounds__(256) void transpose_k(
    const float* __restrict__ query_w, const float* __restrict__ key_w,
    const float* __restrict__ value_w, const float* __restrict__ gating_w,
    u16* __restrict__ wt)
{
    int i = blockIdx.x * 256 + threadIdx.x;   // 0 .. 262143
    int half = i >> 17;
    int rem = i & 131071;
    int h = rem >> 14, e = rem & 16383;
    int n = e >> 8, k = e & 255;
    int src_idx = k * 256 + h * 32 + (n & 31);
    float v;
    if (half == 0) v = (n < 32) ? key_w[src_idx]   : value_w[src_idx];
    else           v = (n < 32) ? query_w[src_idx] : gating_w[src_idx];
    wt[i] = f2bf(v);
}

// ---------------------------------------------------------------------------
// Fused per-(b,h) kernel: K/V projection -> LDS, Q/gate projection -> regs,
// QK^T + bias + softmax + PV per 16-row q-tile, sigmoid gating, write WA bf16.
// LDS: 31488 u16 = 62,976 B
//   Ksh [256][40]  @ 0       (10240)
//   Vt  [32][264]  @ 10240   ( 8448)
//   staging region @ 18688: Xs[256][40] @18688, Wsh[64][40] @28928
//   attention (aliases staging): per-wave @ 18688 + w*2816:
//     Qtile[16][40] (640) + Psh[16][136] (2176)
// ---------------------------------------------------------------------------
__global__ __launch_bounds__(256) void fused_attn_k(
    const float* __restrict__ q_data, const float* __restrict__ m_data,
    const float* __restrict__ bias2, const float* __restrict__ nb,
    const u16* __restrict__ wt, const float* __restrict__ gb,
    u16* __restrict__ WAo)
{
    __shared__ u16 smem[31488];
    u16* Ksh = smem;             // [s][c] stride 40
    u16* Vt  = smem + 10240;     // [c][s] stride 264
    u16* Xs  = smem + 18688;     // [row][k] stride 40
    u16* Wsh = smem + 28928;     // [n][k] stride 40

    int bid = blockIdx.x;
    int b = bid >> 3, h = bid & 7;
    int tid = threadIdx.x, lane = tid & 63, w = tid >> 6;
    int l15 = lane & 15;
    int kl = (lane >> 4) << 3;           // 0,8,16,24
    int rq = (lane >> 4) << 2;           // 0,4,8,12 (C-layout row base)
    const f32x4 fz = {0.f, 0.f, 0.f, 0.f};

    // per-key bias (16 values: key = t*16 + l15), fp32
    float bload[16];
#pragma unroll
    for (int t = 0; t < 16; t++) bload[t] = bias2[(b << 8) + t * 16 + l15];
    float gbc0 = gb[h * 32 + l15];
    float gbc1 = gb[h * 32 + 16 + l15];

    // ---------------- KV projection: [256 x 64] = m_data[b] @ WkvT[h]^T ----
    const float* Xg = m_data + ((size_t)b << 16);
    const u16* Wg = wt + (h << 14);
    f32x4 acc[4][4];
#pragma unroll
    for (int i = 0; i < 4; i++)
#pragma unroll
        for (int j = 0; j < 4; j++) acc[i][j] = fz;

    for (int kb = 0; kb < 8; ++kb) {
        Cvt32 am;
        ld32f_bf(Xg + (size_t)tid * 256 + kb * 32, am);
        u32x4 b0, b1;
        int nrow = tid >> 1, nc = (tid & 1) << 4;
        if (tid < 128) {
            const u16* q = Wg + nrow * 256 + kb * 32 + nc;
            b0 = *(const u32x4*)q; b1 = *(const u32x4*)(q + 8);
        }
        if (kb) __syncthreads();
        *(u32x4*)&Xs[tid * 40]      = am.v[0];
        *(u32x4*)&Xs[tid * 40 + 8]  = am.v[1];
        *(u32x4*)&Xs[tid * 40 + 16] = am.v[2];
        *(u32x4*)&Xs[tid * 40 + 24] = am.v[3];
        if (tid < 128) {
            *(u32x4*)&Wsh[nrow * 40 + nc] = b0;
            *(u32x4*)&Wsh[nrow * 40 + nc + 8] = b1;
        }
        __syncthreads();
        short8 af[4], bf[4];
#pragma unroll
        for (int i = 0; i < 4; i++) af[i] = *(const short8*)&Xs[(64 * w + i * 16 + l15) * 40 + kl];
#pragma unroll
        for (int i = 0; i < 4; i++) bf[i] = *(const short8*)&Wsh[(i * 16 + l15) * 40 + kl];
#pragma unroll
        for (int mi = 0; mi < 4; mi++)
#pragma unroll
            for (int ni = 0; ni < 4; ni++)
                acc[mi][ni] = __builtin_amdgcn_mfma_f32_16x16x32_bf16(af[mi], bf[ni], acc[mi][ni], 0, 0, 0);
    }
    // write K (cols 0..31) to Ksh[s][c], V (cols 32..63) to Vt[c][s]
#pragma unroll
    for (int mi = 0; mi < 4; mi++)
#pragma unroll
        for (int ni = 0; ni < 4; ni++)
#pragma unroll
            for (int r = 0; r < 4; r++) {
                int s = 64 * w + mi * 16 + rq + r;
                int col = ni * 16 + l15;
                u16 v = f2bf(acc[mi][ni][r]);
                if (ni < 2) Ksh[s * 40 + col] = v;
                else        Vt[(col - 32) * 264 + s] = v;
            }
    __syncthreads();

    // ---------------- QG projection: [256 x 64] = q_data[b] @ WqgT[h]^T ----
    const float* Xg2 = q_data + ((size_t)b << 16);
    const u16* Wg2 = wt + 131072 + (h << 14);
    f32x4 acc2[4][4];
#pragma unroll
    for (int i = 0; i < 4; i++)
#pragma unroll
        for (int j = 0; j < 4; j++) acc2[i][j] = fz;

    for (int kb = 0; kb < 8; ++kb) {
        Cvt32 am;
        ld32f_bf(Xg2 + (size_t)tid * 256 + kb * 32, am);
        u32x4 b0, b1;
        int nrow = tid >> 1, nc = (tid & 1) << 4;
        if (tid < 128) {
            const u16* q = Wg2 + nrow * 256 + kb * 32 + nc;
            b0 = *(const u32x4*)q; b1 = *(const u32x4*)(q + 8);
        }
        __syncthreads();   // previous iter's frag reads (or Ksh/Vt writes) done
        *(u32x4*)&Xs[tid * 40]      = am.v[0];
        *(u32x4*)&Xs[tid * 40 + 8]  = am.v[1];
        *(u32x4*)&Xs[tid * 40 + 16] = am.v[2];
        *(u32x4*)&Xs[tid * 40 + 24] = am.v[3];
        if (tid < 128) {
            *(u32x4*)&Wsh[nrow * 40 + nc] = b0;
            *(u32x4*)&Wsh[nrow * 40 + nc + 8] = b1;
        }
        __syncthreads();
        short8 af[4], bf[4];
#pragma unroll
        for (int i = 0; i < 4; i++) af[i] = *(const short8*)&Xs[(64 * w + i * 16 + l15) * 40 + kl];
#pragma unroll
        for (int i = 0; i < 4; i++) bf[i] = *(const short8*)&Wsh[(i * 16 + l15) * 40 + kl];
#pragma unroll
        for (int mi = 0; mi < 4; mi++)
#pragma unroll
            for (int ni = 0; ni < 4; ni++)
                acc2[mi][ni] = __builtin_amdgcn_mfma_f32_16x16x32_bf16(af[mi], bf[ni], acc2[mi][ni], 0, 0, 0);
    }
    __syncthreads();   // staging dead; per-wave Qtile/Psh may now overwrite it

    // ---------------- attention, per 16-row q-tile mt ----------------------
    u16* myQ = smem + 18688 + w * 2816;        // [16][40]
    u16* myP = myQ + 640;                      // [16][136]
    const float* nbp = nb + ((size_t)h << 16);
    const float qscale = 0.17677669529663687f; // 32^-0.5

#pragma unroll 1
    for (int mt = 0; mt < 4; ++mt) {
        // Q tile (16 rows x 32) from acc2[mt][0..1], scaled
#pragma unroll
        for (int ni = 0; ni < 2; ++ni)
#pragma unroll
            for (int r = 0; r < 4; r++)
                myQ[(rq + r) * 40 + ni * 16 + l15] = f2bf(acc2[mt][ni][r] * qscale);

        short8 qf = *(const short8*)&myQ[l15 * 40 + kl];
        f32x4 sc[16];
#pragma unroll
        for (int t = 0; t < 16; t++) {
            short8 kf = *(const short8*)&Ksh[(t * 16 + l15) * 40 + kl];
            sc[t] = __builtin_amdgcn_mfma_f32_16x16x32_bf16(qf, kf, fz, 0, 0, 0);
        }

        int q0 = 64 * w + mt * 16 + rq;        // first of this lane's 4 q rows
        float mrow[4] = {-3e30f, -3e30f, -3e30f, -3e30f};
#pragma unroll
        for (int t = 0; t < 16; t++) {
            int kidx = t * 16 + l15;
#pragma unroll
            for (int r = 0; r < 4; r++) {
                float v = sc[t][r] + bload[t] + nbp[(size_t)(q0 + r) * 256 + kidx];
                sc[t][r] = v;
                mrow[r] = fmaxf(mrow[r], v);
            }
        }
#pragma unroll
        for (int r = 0; r < 4; r++) {
            float m = mrow[r];
            m = fmaxf(m, __shfl_xor(m, 1));
            m = fmaxf(m, __shfl_xor(m, 2));
            m = fmaxf(m, __shfl_xor(m, 4));
            m = fmaxf(m, __shfl_xor(m, 8));
            mrow[r] = m;
        }
        float srow[4] = {0.f, 0.f, 0.f, 0.f};
#pragma unroll
        for (int t = 0; t < 16; t++)
#pragma unroll
            for (int r = 0; r < 4; r++) {
                float p = __expf(sc[t][r] - mrow[r]);
                sc[t][r] = p;
                srow[r] += p;
            }
#pragma unroll
        for (int r = 0; r < 4; r++) {
            float s = srow[r];
            s += __shfl_xor(s, 1);
            s += __shfl_xor(s, 2);
            s += __shfl_xor(s, 4);
            s += __shfl_xor(s, 8);
            srow[r] = 1.f / s;
        }

        f32x4 oacc[2] = {fz, fz};
        // PV in two key-halves through the half-width P buffer (wave-private)
#pragma unroll
        for (int half = 0; half < 2; ++half) {
#pragma unroll
            for (int t = 0; t < 8; t++)
#pragma unroll
                for (int r = 0; r < 4; r++)
                    myP[(rq + r) * 136 + t * 16 + l15] =
                        f2bf(sc[half * 8 + t][r] * srow[r]);
#pragma unroll
            for (int ks = 0; ks < 4; ++ks) {
                short8 pf = *(const short8*)&myP[l15 * 136 + ks * 32 + kl];
#pragma unroll
                for (int ni = 0; ni < 2; ++ni) {
                    short8 vf = *(const short8*)&Vt[(ni * 16 + l15) * 264 + half * 128 + ks * 32 + kl];
                    oacc[ni] = __builtin_amdgcn_mfma_f32_16x16x32_bf16(pf, vf, oacc[ni], 0, 0, 0);
                }
            }
        }

        // gated store: WA[b, q, h*32 + c] (bf16)
#pragma unroll
        for (int ni = 0; ni < 2; ++ni) {
            float gbv = ni ? gbc1 : gbc0;
#pragma unroll
            for (int r = 0; r < 4; r++) {
                float gate = 1.f / (1.f + __expf(-(acc2[mt][ni + 2][r] + gbv)));
                size_t idx = (((size_t)b << 8) + q0 + r) * 256 + h * 32 + ni * 16 + l15;
                WAo[idx] = f2bf(oacc[ni][r] * gate);
            }
        }
    }
}

// ---------------------------------------------------------------------------
// Output GEMM: out[65536,256] = WA(bf16) @ output_w(fp32) + output_b, fp32 out.
// output_w is read UNtransposed; transpose+convert happens in the B-staging
// scatter. 128x128 tile, same MFMA structure.
// ---------------------------------------------------------------------------
__global__ __launch_bounds__(256) void gemm_out_k(
    const u16* __restrict__ X, const float* __restrict__ Wo,
    float* __restrict__ dst, const float* __restrict__ cbias)
{
    __shared__ u16 As[128 * 40];
    __shared__ u16 Bs[128 * 40];
    int tid = threadIdx.x;
    int lane = tid & 63, w = tid >> 6;
    int wm = w >> 1, wn = w & 1;
    int row0 = blockIdx.x * 128;
    int n0 = blockIdx.y * 128;
    int lr = tid >> 1;
    int lc = (tid & 1) << 4;

    const f32x4 fz = {0.f, 0.f, 0.f, 0.f};
    f32x4 acc[4][4];
#pragma unroll
    for (int i = 0; i < 4; i++)
#pragma unroll
        for (int j = 0; j < 4; j++) acc[i][j] = fz;

    int kl = (lane >> 4) << 3;
    int l15 = lane & 15;
    int rm = wm * 64 + l15;
    int rn = wn * 64 + l15;

    for (int kb = 0; kb < 8; ++kb) {
        int k0 = kb << 5;
        const u16* pa = X + ((size_t)(row0 + lr) << 8) + k0 + lc;
        u32x4 a0 = *(const u32x4*)pa;
        u32x4 a1 = *(const u32x4*)(pa + 8);
        // B: thread t loads Wo row k = k0 + (t>>3), 16 fp32 cols at n0+(t&7)*16
        int bk = tid >> 3, bn = (tid & 7) << 4;
        const float* pb = Wo + (size_t)(k0 + bk) * 256 + n0 + bn;
        u16 bu[16];
#pragma unroll
        for (int j = 0; j < 16; j += 4) {
            f32x4 x = *(const f32x4*)(pb + j);
            bu[j] = f2bf(x[0]); bu[j + 1] = f2bf(x[1]);
            bu[j + 2] = f2bf(x[2]); bu[j + 3] = f2bf(x[3]);
        }
        if (kb) __syncthreads();
        *(u32x4*)&As[lr * 40 + lc] = a0;
        *(u32x4*)&As[lr * 40 + lc + 8] = a1;
#pragma unroll
        for (int j = 0; j < 16; j++) Bs[(bn + j) * 40 + bk] = bu[j];
        __syncthreads();
        short8 af[4], bf[4];
#pragma unroll
        for (int i = 0; i < 4; i++) af[i] = *(const short8*)&As[(rm + i * 16) * 40 + kl];
#pragma unroll
        for (int i = 0; i < 4; i++) bf[i] = *(const short8*)&Bs[(rn + i * 16) * 40 + kl];
#pragma unroll
        for (int mi = 0; mi < 4; mi++)
#pragma unroll
            for (int ni = 0; ni < 4; ni++)
                acc[mi][ni] = __builtin_amdgcn_mfma_f32_16x16x32_bf16(af[mi], bf[ni], acc[mi][ni], 0, 0, 0);
    }

#pragma unroll
    for (int mi = 0; mi < 4; mi++)
#pragma unroll
        for (int ni = 0; ni < 4; ni++)
#pragma unroll
            for (int r = 0; r < 4; r++) {
                int row = row0 + wm * 64 + mi * 16 + ((lane >> 4) << 2) + r;
                int col = n0 + wn * 64 + ni * 16 + l15;
                dst[((size_t)row << 8) + col] = acc[mi][ni][r] + cbias[col];
            }
}

// ---------------------------------------------------------------------------
extern "C" void kernel_launch(void* const* d_in, const int* in_sizes, int n_in,
                              void* d_out, int out_size, void* d_ws, size_t ws_size,
                              hipStream_t stream)
{
    const float* q_data   = (const float*)d_in[0];
    const float* m_data   = (const float*)d_in[1];
    const float* bias     = (const float*)d_in[2];
    const float* nb       = (const float*)d_in[3];
    const float* query_w  = (const float*)d_in[4];
    const float* key_w    = (const float*)d_in[5];
    const float* value_w  = (const float*)d_in[6];
    const float* gating_w = (const float*)d_in[7];
    const float* gating_b = (const float*)d_in[8];
    const float* output_w = (const float*)d_in[9];
    const float* output_b = (const float*)d_in[10];

    u16* WAb = (u16*)d_ws;          // 16,777,216 u16 = 32 MiB (entire ws need)
    u16* wt  = (u16*)d_out;         // per-head transposed bf16 weights (512 KiB)
                                    // in d_out scratch, dead until final GEMM

    transpose_k<<<1024, 256, 0, stream>>>(query_w, key_w, value_w, gating_w, wt);

    fused_attn_k<<<2048, 256, 0, stream>>>(q_data, m_data, bias, nb, wt, gating_b, WAb);

    gemm_out_k<<<dim3(512, 2), 256, 0, stream>>>(WAb, output_w, (float*)d_out, output_b);
}

// Round 5
// 477.571 us; speedup vs baseline: 1.4774x; 1.4774x over previous
//
#include <hip/hip_runtime.h>

typedef unsigned short u16;
typedef __attribute__((ext_vector_type(8))) short short8;
typedef __attribute__((ext_vector_type(4))) float f32x4;
typedef __attribute__((ext_vector_type(4))) unsigned int u32x4;
typedef __attribute__((ext_vector_type(4))) unsigned short u16x4;

__device__ __forceinline__ float bf2f(u16 u) {
    union { float f; unsigned int i; } c; c.i = ((unsigned int)u) << 16; return c.f;
}
__device__ __forceinline__ u16 f2bf(float f) {
    unsigned int x = __float_as_uint(f);
    x += 0x7fff + ((x >> 16) & 1);   // RNE
    return (u16)(x >> 16);
}

union Cvt32 { u32x4 v[4]; u16 u[32]; };

// load 32 consecutive fp32 and convert to 32 bf16
__device__ __forceinline__ void ld32f_bf(const float* __restrict__ p, Cvt32& t) {
#pragma unroll
    for (int j = 0; j < 32; j += 4) {
        f32x4 x = *(const f32x4*)(p + j);
        t.u[j]     = f2bf(x[0]);
        t.u[j + 1] = f2bf(x[1]);
        t.u[j + 2] = f2bf(x[2]);
        t.u[j + 3] = f2bf(x[3]);
    }
}

// ===========================================================================
// ============================ PATH A (large ws) ============================
// ===========================================================================

// Prep: q_data/m_data -> bf16 (into d_out scratch), nb -> bf16, proj weights
// -> wt[n=0..1023][k] bf16 (n: 0-255 key, 256-511 value, 512-767 query,
// 768-1023 gating; n&255 == h*32+c matches source (k,h,c) flattening),
// output_w -> WoT[o][k=h*32+c].
__global__ __launch_bounds__(256) void prep_a(
    const float* __restrict__ q_data, const float* __restrict__ m_data,
    const float* __restrict__ nb,
    const float* __restrict__ qw, const float* __restrict__ kw,
    const float* __restrict__ vw, const float* __restrict__ gw,
    const float* __restrict__ ow,
    u16* __restrict__ qbf, u16* __restrict__ mbf, u16* __restrict__ nbbf,
    u16* __restrict__ wt, u16* __restrict__ WoT)
{
    int blk = blockIdx.x, tid = threadIdx.x;
    if (blk < 32768) {
        const float* src = (blk < 16384) ? q_data : m_data;
        u16* dst = (blk < 16384) ? qbf : mbf;
        int i = (blk & 16383) * 1024 + tid * 4;
        f32x4 x = *(const f32x4*)(src + i);
        u16x4 o = { f2bf(x[0]), f2bf(x[1]), f2bf(x[2]), f2bf(x[3]) };
        *(u16x4*)(dst + i) = o;
    } else if (blk < 33280) {
        int i = (blk - 32768) * 1024 + tid * 4;
        f32x4 x = *(const f32x4*)(nb + i);
        u16x4 o = { f2bf(x[0]), f2bf(x[1]), f2bf(x[2]), f2bf(x[3]) };
        *(u16x4*)(nbbf + i) = o;
    } else if (blk < 34304) {
        int e = (blk - 33280) * 256 + tid;   // 0..262143
        int n = e & 255, k = (e >> 8) & 255, g = e >> 16;
        const float* W = g == 0 ? kw : g == 1 ? vw : g == 2 ? qw : gw;
        wt[(((g << 8) | n) << 8) | k] = f2bf(W[k * 256 + n]);
    } else {
        int e = (blk - 34304) * 256 + tid;   // 0..65535
        int o = e & 255, hc = e >> 8;
        WoT[o * 256 + hc] = f2bf(ow[hc * 256 + o]);
    }
}

// Projection GEMM: C[65536 x 1024] = X @ W, X = mbf (n<512) or qbf (n>=512).
// 128x128 tile, 4 waves 2x2, 4x4 16x16x32 MFMAs. Epilogue scatters to
// per-head (b,h,s,c) layouts: K, V, Q*scale, G+gating_b.
__global__ __launch_bounds__(256) void proj_a(
    const u16* __restrict__ mbf, const u16* __restrict__ qbf,
    const u16* __restrict__ wt,
    u16* __restrict__ Kh, u16* __restrict__ Vh, u16* __restrict__ Qh,
    u16* __restrict__ GW, const float* __restrict__ gb)
{
    __shared__ u16 As[128 * 40];
    __shared__ u16 Bs[128 * 40];
    int tid = threadIdx.x;
    int lane = tid & 63, w = tid >> 6;
    int wm = w >> 1, wn = w & 1;
    int row0 = blockIdx.x * 128;
    int n0 = blockIdx.y * 128;          // 0..896
    int g = blockIdx.y >> 1;            // weight group
    const u16* X = (g < 2) ? mbf : qbf;
    int lr = tid >> 1;
    int lc = (tid & 1) << 4;

    const f32x4 fz = {0.f, 0.f, 0.f, 0.f};
    f32x4 acc[4][4];
#pragma unroll
    for (int i = 0; i < 4; i++)
#pragma unroll
        for (int j = 0; j < 4; j++) acc[i][j] = fz;

    int kl = (lane >> 4) << 3;
    int l15 = lane & 15;
    int rm = wm * 64 + l15;
    int rn = wn * 64 + l15;

    for (int kb = 0; kb < 8; ++kb) {
        int k0 = kb << 5;
        const u16* pa = X + ((size_t)(row0 + lr) << 8) + k0 + lc;
        u32x4 a0 = *(const u32x4*)pa;
        u32x4 a1 = *(const u32x4*)(pa + 8);
        const u16* pb = wt + ((size_t)(n0 + lr) << 8) + k0 + lc;
        u32x4 b0 = *(const u32x4*)pb;
        u32x4 b1 = *(const u32x4*)(pb + 8);
        if (kb) __syncthreads();
        *(u32x4*)&As[lr * 40 + lc] = a0;
        *(u32x4*)&As[lr * 40 + lc + 8] = a1;
        *(u32x4*)&Bs[lr * 40 + lc] = b0;
        *(u32x4*)&Bs[lr * 40 + lc + 8] = b1;
        __syncthreads();
        short8 af[4], bf[4];
#pragma unroll
        for (int i = 0; i < 4; i++) af[i] = *(const short8*)&As[(rm + i * 16) * 40 + kl];
#pragma unroll
        for (int i = 0; i < 4; i++) bf[i] = *(const short8*)&Bs[(rn + i * 16) * 40 + kl];
#pragma unroll
        for (int mi = 0; mi < 4; mi++)
#pragma unroll
            for (int ni = 0; ni < 4; ni++)
                acc[mi][ni] = __builtin_amdgcn_mfma_f32_16x16x32_bf16(af[mi], bf[ni], acc[mi][ni], 0, 0, 0);
    }

    u16* dst = (g == 0) ? Kh : (g == 1) ? Vh : (g == 2) ? Qh : GW;
    float scale = (g == 2) ? 0.17677669529663687f : 1.f;
#pragma unroll
    for (int mi = 0; mi < 4; mi++)
#pragma unroll
        for (int ni = 0; ni < 4; ni++)
#pragma unroll
            for (int r = 0; r < 4; r++) {
                int row = row0 + wm * 64 + mi * 16 + ((lane >> 4) << 2) + r;
                int col = n0 + wn * 64 + ni * 16 + l15;
                float v = acc[mi][ni][r] * scale;
                int hc = col & 255;
                if (g == 3) v += gb[hc];
                int b = row >> 8, s = row & 255, h = hc >> 5, c = col & 31;
                dst[((((size_t)b * 8 + h) << 8) + s) * 32 + c] = f2bf(v);
            }
}

// Lean attention per (b,h): stage K/V (bf16, 16 KiB each), Q frags straight
// from global, QK^T + bias + nb(bf16) + softmax + PV, sigmoid-gate from GW
// and write WA in-place over GW (block-private region).
__global__ __launch_bounds__(256) void attn_a(
    const u16* __restrict__ Qh, const u16* __restrict__ Kh,
    const u16* __restrict__ Vh, u16* GW,
    const float* __restrict__ bias2, const u16* __restrict__ nbbf)
{
    __shared__ u16 smem[27392];          // 54,784 B
    u16* Ksh = smem;                     // [256][40]
    u16* Vt  = smem + 10240;             // [32][264]
    // per-wave P @ 18688 + w*2176 : [16][136]

    int bid = blockIdx.x;
    int b = bid >> 3, h = bid & 7;
    int tid = threadIdx.x, lane = tid & 63, w = tid >> 6;
    int l15 = lane & 15;
    int kl = (lane >> 4) << 3;
    int rq = (lane >> 4) << 2;
    size_t hoff = ((size_t)(b * 8 + h)) << 13;
    const f32x4 fz = {0.f, 0.f, 0.f, 0.f};

    {   // stage K rows
        const u16* p = Kh + hoff + (tid << 5);
        u32x4 v0 = *(const u32x4*)p,        v1 = *(const u32x4*)(p + 8);
        u32x4 v2 = *(const u32x4*)(p + 16), v3 = *(const u32x4*)(p + 24);
        *(u32x4*)&Ksh[tid * 40] = v0;      *(u32x4*)&Ksh[tid * 40 + 8] = v1;
        *(u32x4*)&Ksh[tid * 40 + 16] = v2; *(u32x4*)&Ksh[tid * 40 + 24] = v3;
    }
    {   // stage V transposed
        const u16* p = Vh + hoff + (tid << 5);
        Cvt32 tm;
        tm.v[0] = *(const u32x4*)p;        tm.v[1] = *(const u32x4*)(p + 8);
        tm.v[2] = *(const u32x4*)(p + 16); tm.v[3] = *(const u32x4*)(p + 24);
#pragma unroll
        for (int c = 0; c < 32; c++) Vt[c * 264 + tid] = tm.u[c];
    }
    float bload[16];
#pragma unroll
    for (int t = 0; t < 16; t++) bload[t] = bias2[(b << 8) + t * 16 + l15];
    // Q fragments (A-layout contiguous in global)
    short8 qf[4];
#pragma unroll
    for (int mt = 0; mt < 4; mt++)
        qf[mt] = *(const short8*)(Qh + hoff + (size_t)(64 * w + mt * 16 + l15) * 32 + kl);
    __syncthreads();

    short8 kf[16];
#pragma unroll
    for (int t = 0; t < 16; t++) kf[t] = *(const short8*)&Ksh[(t * 16 + l15) * 40 + kl];

    u16* myP = smem + 18688 + w * 2176;
    const u16* nbp = nbbf + ((size_t)h << 16);

#pragma unroll 1
    for (int mt = 0; mt < 4; ++mt) {
        f32x4 sc[16];
#pragma unroll
        for (int t = 0; t < 16; t++)
            sc[t] = __builtin_amdgcn_mfma_f32_16x16x32_bf16(qf[mt], kf[t], fz, 0, 0, 0);

        int q0 = 64 * w + mt * 16 + rq;
        float mrow[4] = {-3e30f, -3e30f, -3e30f, -3e30f};
#pragma unroll
        for (int t = 0; t < 16; t++) {
            int kidx = t * 16 + l15;
#pragma unroll
            for (int r = 0; r < 4; r++) {
                float v = sc[t][r] + bload[t] + bf2f(nbp[(size_t)(q0 + r) * 256 + kidx]);
                sc[t][r] = v;
                mrow[r] = fmaxf(mrow[r], v);
            }
        }
#pragma unroll
        for (int r = 0; r < 4; r++) {
            float m = mrow[r];
            m = fmaxf(m, __shfl_xor(m, 1));
            m = fmaxf(m, __shfl_xor(m, 2));
            m = fmaxf(m, __shfl_xor(m, 4));
            m = fmaxf(m, __shfl_xor(m, 8));
            mrow[r] = m;
        }
        float srow[4] = {0.f, 0.f, 0.f, 0.f};
#pragma unroll
        for (int t = 0; t < 16; t++)
#pragma unroll
            for (int r = 0; r < 4; r++) {
                float p = __expf(sc[t][r] - mrow[r]);
                sc[t][r] = p;
                srow[r] += p;
            }
#pragma unroll
        for (int r = 0; r < 4; r++) {
            float s = srow[r];
            s += __shfl_xor(s, 1);
            s += __shfl_xor(s, 2);
            s += __shfl_xor(s, 4);
            s += __shfl_xor(s, 8);
            srow[r] = 1.f / s;
        }

        f32x4 oacc[2] = {fz, fz};
#pragma unroll
        for (int half = 0; half < 2; ++half) {
#pragma unroll
            for (int t = 0; t < 8; t++)
#pragma unroll
                for (int r = 0; r < 4; r++)
                    myP[(rq + r) * 136 + t * 16 + l15] =
                        f2bf(sc[half * 8 + t][r] * srow[r]);
#pragma unroll
            for (int ks = 0; ks < 4; ++ks) {
                short8 pf = *(const short8*)&myP[l15 * 136 + ks * 32 + kl];
#pragma unroll
                for (int ni = 0; ni < 2; ++ni) {
                    short8 vf = *(const short8*)&Vt[(ni * 16 + l15) * 264 + half * 128 + ks * 32 + kl];
                    oacc[ni] = __builtin_amdgcn_mfma_f32_16x16x32_bf16(pf, vf, oacc[ni], 0, 0, 0);
                }
            }
        }

        // gate (read) then overwrite same element with gated WA — block-private
#pragma unroll
        for (int ni = 0; ni < 2; ++ni)
#pragma unroll
            for (int r = 0; r < 4; r++) {
                size_t idx = hoff + (size_t)(q0 + r) * 32 + ni * 16 + l15;
                float gate = 1.f / (1.f + __expf(-bf2f(GW[idx])));
                GW[idx] = f2bf(oacc[ni][r] * gate);
            }
    }
}

// Output GEMM: out[65536,256] = WA(b,h,s,c) @ WoT^T + output_b (fp32 out).
// K-slice kb == head kb, so A-tiles stay coalesced in the (b,h,s,c) layout.
__global__ __launch_bounds__(256) void gemmout_a(
    const u16* __restrict__ WA, const u16* __restrict__ WoT,
    float* __restrict__ dst, const float* __restrict__ ob)
{
    __shared__ u16 As[128 * 40];
    __shared__ u16 Bs[128 * 40];
    int tid = threadIdx.x;
    int lane = tid & 63, w = tid >> 6;
    int wm = w >> 1, wn = w & 1;
    int row0 = blockIdx.x * 128;
    int n0 = blockIdx.y * 128;
    int bq = row0 >> 8, s0 = row0 & 255;
    int lr = tid >> 1;
    int lc = (tid & 1) << 4;

    const f32x4 fz = {0.f, 0.f, 0.f, 0.f};
    f32x4 acc[4][4];
#pragma unroll
    for (int i = 0; i < 4; i++)
#pragma unroll
        for (int j = 0; j < 4; j++) acc[i][j] = fz;

    int kl = (lane >> 4) << 3;
    int l15 = lane & 15;
    int rm = wm * 64 + l15;
    int rn = wn * 64 + l15;

    for (int kb = 0; kb < 8; ++kb) {
        int k0 = kb << 5;
        const u16* pa = WA + ((((size_t)bq * 8 + kb) << 8) + s0 + lr) * 32 + lc;
        u32x4 a0 = *(const u32x4*)pa;
        u32x4 a1 = *(const u32x4*)(pa + 8);
        const u16* pb = WoT + ((size_t)(n0 + lr) << 8) + k0 + lc;
        u32x4 b0 = *(const u32x4*)pb;
        u32x4 b1 = *(const u32x4*)(pb + 8);
        if (kb) __syncthreads();
        *(u32x4*)&As[lr * 40 + lc] = a0;
        *(u32x4*)&As[lr * 40 + lc + 8] = a1;
        *(u32x4*)&Bs[lr * 40 + lc] = b0;
        *(u32x4*)&Bs[lr * 40 + lc + 8] = b1;
        __syncthreads();
        short8 af[4], bf[4];
#pragma unroll
        for (int i = 0; i < 4; i++) af[i] = *(const short8*)&As[(rm + i * 16) * 40 + kl];
#pragma unroll
        for (int i = 0; i < 4; i++) bf[i] = *(const short8*)&Bs[(rn + i * 16) * 40 + kl];
#pragma unroll
        for (int mi = 0; mi < 4; mi++)
#pragma unroll
            for (int ni = 0; ni < 4; ni++)
                acc[mi][ni] = __builtin_amdgcn_mfma_f32_16x16x32_bf16(af[mi], bf[ni], acc[mi][ni], 0, 0, 0);
    }

#pragma unroll
    for (int mi = 0; mi < 4; mi++)
#pragma unroll
        for (int ni = 0; ni < 4; ni++)
#pragma unroll
            for (int r = 0; r < 4; r++) {
                int row = row0 + wm * 64 + mi * 16 + ((lane >> 4) << 2) + r;
                int col = n0 + wn * 64 + ni * 16 + l15;
                dst[((size_t)row << 8) + col] = acc[mi][ni][r] + ob[col];
            }
}

// ===========================================================================
// ===================== PATH B (small ws) — round-4 code ====================
// ===========================================================================

__global__ __launch_bounds__(256) void transpose_k(
    const float* __restrict__ query_w, const float* __restrict__ key_w,
    const float* __restrict__ value_w, const float* __restrict__ gating_w,
    u16* __restrict__ wt)
{
    int i = blockIdx.x * 256 + threadIdx.x;
    int half = i >> 17;
    int rem = i & 131071;
    int h = rem >> 14, e = rem & 16383;
    int n = e >> 8, k = e & 255;
    int src_idx = k * 256 + h * 32 + (n & 31);
    float v;
    if (half == 0) v = (n < 32) ? key_w[src_idx]   : value_w[src_idx];
    else           v = (n < 32) ? query_w[src_idx] : gating_w[src_idx];
    wt[i] = f2bf(v);
}

__global__ __launch_bounds__(256) void fused_attn_k(
    const float* __restrict__ q_data, const float* __restrict__ m_data,
    const float* __restrict__ bias2, const float* __restrict__ nb,
    const u16* __restrict__ wt, const float* __restrict__ gb,
    u16* __restrict__ WAo)
{
    __shared__ u16 smem[31488];
    u16* Ksh = smem;
    u16* Vt  = smem + 10240;
    u16* Xs  = smem + 18688;
    u16* Wsh = smem + 28928;

    int bid = blockIdx.x;
    int b = bid >> 3, h = bid & 7;
    int tid = threadIdx.x, lane = tid & 63, w = tid >> 6;
    int l15 = lane & 15;
    int kl = (lane >> 4) << 3;
    int rq = (lane >> 4) << 2;
    const f32x4 fz = {0.f, 0.f, 0.f, 0.f};

    float bload[16];
#pragma unroll
    for (int t = 0; t < 16; t++) bload[t] = bias2[(b << 8) + t * 16 + l15];
    float gbc0 = gb[h * 32 + l15];
    float gbc1 = gb[h * 32 + 16 + l15];

    const float* Xg = m_data + ((size_t)b << 16);
    const u16* Wg = wt + (h << 14);
    f32x4 acc[4][4];
#pragma unroll
    for (int i = 0; i < 4; i++)
#pragma unroll
        for (int j = 0; j < 4; j++) acc[i][j] = fz;

    for (int kb = 0; kb < 8; ++kb) {
        Cvt32 am;
        ld32f_bf(Xg + (size_t)tid * 256 + kb * 32, am);
        u32x4 b0, b1;
        int nrow = tid >> 1, nc = (tid & 1) << 4;
        if (tid < 128) {
            const u16* q = Wg + nrow * 256 + kb * 32 + nc;
            b0 = *(const u32x4*)q; b1 = *(const u32x4*)(q + 8);
        }
        if (kb) __syncthreads();
        *(u32x4*)&Xs[tid * 40]      = am.v[0];
        *(u32x4*)&Xs[tid * 40 + 8]  = am.v[1];
        *(u32x4*)&Xs[tid * 40 + 16] = am.v[2];
        *(u32x4*)&Xs[tid * 40 + 24] = am.v[3];
        if (tid < 128) {
            *(u32x4*)&Wsh[nrow * 40 + nc] = b0;
            *(u32x4*)&Wsh[nrow * 40 + nc + 8] = b1;
        }
        __syncthreads();
        short8 af[4], bf[4];
#pragma unroll
        for (int i = 0; i < 4; i++) af[i] = *(const short8*)&Xs[(64 * w + i * 16 + l15) * 40 + kl];
#pragma unroll
        for (int i = 0; i < 4; i++) bf[i] = *(const short8*)&Wsh[(i * 16 + l15) * 40 + kl];
#pragma unroll
        for (int mi = 0; mi < 4; mi++)
#pragma unroll
            for (int ni = 0; ni < 4; ni++)
                acc[mi][ni] = __builtin_amdgcn_mfma_f32_16x16x32_bf16(af[mi], bf[ni], acc[mi][ni], 0, 0, 0);
    }
#pragma unroll
    for (int mi = 0; mi < 4; mi++)
#pragma unroll
        for (int ni = 0; ni < 4; ni++)
#pragma unroll
            for (int r = 0; r < 4; r++) {
                int s = 64 * w + mi * 16 + rq + r;
                int col = ni * 16 + l15;
                u16 v = f2bf(acc[mi][ni][r]);
                if (ni < 2) Ksh[s * 40 + col] = v;
                else        Vt[(col - 32) * 264 + s] = v;
            }
    __syncthreads();

    const float* Xg2 = q_data + ((size_t)b << 16);
    const u16* Wg2 = wt + 131072 + (h << 14);
    f32x4 acc2[4][4];
#pragma unroll
    for (int i = 0; i < 4; i++)
#pragma unroll
        for (int j = 0; j < 4; j++) acc2[i][j] = fz;

    for (int kb = 0; kb < 8; ++kb) {
        Cvt32 am;
        ld32f_bf(Xg2 + (size_t)tid * 256 + kb * 32, am);
        u32x4 b0, b1;
        int nrow = tid >> 1, nc = (tid & 1) << 4;
        if (tid < 128) {
            const u16* q = Wg2 + nrow * 256 + kb * 32 + nc;
            b0 = *(const u32x4*)q; b1 = *(const u32x4*)(q + 8);
        }
        __syncthreads();
        *(u32x4*)&Xs[tid * 40]      = am.v[0];
        *(u32x4*)&Xs[tid * 40 + 8]  = am.v[1];
        *(u32x4*)&Xs[tid * 40 + 16] = am.v[2];
        *(u32x4*)&Xs[tid * 40 + 24] = am.v[3];
        if (tid < 128) {
            *(u32x4*)&Wsh[nrow * 40 + nc] = b0;
            *(u32x4*)&Wsh[nrow * 40 + nc + 8] = b1;
        }
        __syncthreads();
        short8 af[4], bf[4];
#pragma unroll
        for (int i = 0; i < 4; i++) af[i] = *(const short8*)&Xs[(64 * w + i * 16 + l15) * 40 + kl];
#pragma unroll
        for (int i = 0; i < 4; i++) bf[i] = *(const short8*)&Wsh[(i * 16 + l15) * 40 + kl];
#pragma unroll
        for (int mi = 0; mi < 4; mi++)
#pragma unroll
            for (int ni = 0; ni < 4; ni++)
                acc2[mi][ni] = __builtin_amdgcn_mfma_f32_16x16x32_bf16(af[mi], bf[ni], acc2[mi][ni], 0, 0, 0);
    }
    __syncthreads();

    u16* myQ = smem + 18688 + w * 2816;
    u16* myP = myQ + 640;
    const float* nbp = nb + ((size_t)h << 16);
    const float qscale = 0.17677669529663687f;

#pragma unroll 1
    for (int mt = 0; mt < 4; ++mt) {
#pragma unroll
        for (int ni = 0; ni < 2; ++ni)
#pragma unroll
            for (int r = 0; r < 4; r++)
                myQ[(rq + r) * 40 + ni * 16 + l15] = f2bf(acc2[mt][ni][r] * qscale);

        short8 qf = *(const short8*)&myQ[l15 * 40 + kl];
        f32x4 sc[16];
#pragma unroll
        for (int t = 0; t < 16; t++) {
            short8 kfr = *(const short8*)&Ksh[(t * 16 + l15) * 40 + kl];
            sc[t] = __builtin_amdgcn_mfma_f32_16x16x32_bf16(qf, kfr, fz, 0, 0, 0);
        }

        int q0 = 64 * w + mt * 16 + rq;
        float mrow[4] = {-3e30f, -3e30f, -3e30f, -3e30f};
#pragma unroll
        for (int t = 0; t < 16; t++) {
            int kidx = t * 16 + l15;
#pragma unroll
            for (int r = 0; r < 4; r++) {
                float v = sc[t][r] + bload[t] + nbp[(size_t)(q0 + r) * 256 + kidx];
                sc[t][r] = v;
                mrow[r] = fmaxf(mrow[r], v);
            }
        }
#pragma unroll
        for (int r = 0; r < 4; r++) {
            float m = mrow[r];
            m = fmaxf(m, __shfl_xor(m, 1));
            m = fmaxf(m, __shfl_xor(m, 2));
            m = fmaxf(m, __shfl_xor(m, 4));
            m = fmaxf(m, __shfl_xor(m, 8));
            mrow[r] = m;
        }
        float srow[4] = {0.f, 0.f, 0.f, 0.f};
#pragma unroll
        for (int t = 0; t < 16; t++)
#pragma unroll
            for (int r = 0; r < 4; r++) {
                float p = __expf(sc[t][r] - mrow[r]);
                sc[t][r] = p;
                srow[r] += p;
            }
#pragma unroll
        for (int r = 0; r < 4; r++) {
            float s = srow[r];
            s += __shfl_xor(s, 1);
            s += __shfl_xor(s, 2);
            s += __shfl_xor(s, 4);
            s += __shfl_xor(s, 8);
            srow[r] = 1.f / s;
        }

        f32x4 oacc[2] = {fz, fz};
#pragma unroll
        for (int half = 0; half < 2; ++half) {
#pragma unroll
            for (int t = 0; t < 8; t++)
#pragma unroll
                for (int r = 0; r < 4; r++)
                    myP[(rq + r) * 136 + t * 16 + l15] =
                        f2bf(sc[half * 8 + t][r] * srow[r]);
#pragma unroll
            for (int ks = 0; ks < 4; ++ks) {
                short8 pf = *(const short8*)&myP[l15 * 136 + ks * 32 + kl];
#pragma unroll
                for (int ni = 0; ni < 2; ++ni) {
                    short8 vf = *(const short8*)&Vt[(ni * 16 + l15) * 264 + half * 128 + ks * 32 + kl];
                    oacc[ni] = __builtin_amdgcn_mfma_f32_16x16x32_bf16(pf, vf, oacc[ni], 0, 0, 0);
                }
            }
        }

#pragma unroll
        for (int ni = 0; ni < 2; ++ni) {
            float gbv = ni ? gbc1 : gbc0;
#pragma unroll
            for (int r = 0; r < 4; r++) {
                float gate = 1.f / (1.f + __expf(-(acc2[mt][ni + 2][r] + gbv)));
                size_t idx = (((size_t)b << 8) + q0 + r) * 256 + h * 32 + ni * 16 + l15;
                WAo[idx] = f2bf(oacc[ni][r] * gate);
            }
        }
    }
}

__global__ __launch_bounds__(256) void gemm_out_k(
    const u16* __restrict__ X, const float* __restrict__ Wo,
    float* __restrict__ dst, const float* __restrict__ cbias)
{
    __shared__ u16 As[128 * 40];
    __shared__ u16 Bs[128 * 40];
    int tid = threadIdx.x;
    int lane = tid & 63, w = tid >> 6;
    int wm = w >> 1, wn = w & 1;
    int row0 = blockIdx.x * 128;
    int n0 = blockIdx.y * 128;
    int lr = tid >> 1;
    int lc = (tid & 1) << 4;

    const f32x4 fz = {0.f, 0.f, 0.f, 0.f};
    f32x4 acc[4][4];
#pragma unroll
    for (int i = 0; i < 4; i++)
#pragma unroll
        for (int j = 0; j < 4; j++) acc[i][j] = fz;

    int kl = (lane >> 4) << 3;
    int l15 = lane & 15;
    int rm = wm * 64 + l15;
    int rn = wn * 64 + l15;

    for (int kb = 0; kb < 8; ++kb) {
        int k0 = kb << 5;
        const u16* pa = X + ((size_t)(row0 + lr) << 8) + k0 + lc;
        u32x4 a0 = *(const u32x4*)pa;
        u32x4 a1 = *(const u32x4*)(pa + 8);
        int bk = tid >> 3, bn = (tid & 7) << 4;
        const float* pb = Wo + (size_t)(k0 + bk) * 256 + n0 + bn;
        u16 bu[16];
#pragma unroll
        for (int j = 0; j < 16; j += 4) {
            f32x4 x = *(const f32x4*)(pb + j);
            bu[j] = f2bf(x[0]); bu[j + 1] = f2bf(x[1]);
            bu[j + 2] = f2bf(x[2]); bu[j + 3] = f2bf(x[3]);
        }
        if (kb) __syncthreads();
        *(u32x4*)&As[lr * 40 + lc] = a0;
        *(u32x4*)&As[lr * 40 + lc + 8] = a1;
#pragma unroll
        for (int j = 0; j < 16; j++) Bs[(bn + j) * 40 + bk] = bu[j];
        __syncthreads();
        short8 af[4], bf[4];
#pragma unroll
        for (int i = 0; i < 4; i++) af[i] = *(const short8*)&As[(rm + i * 16) * 40 + kl];
#pragma unroll
        for (int i = 0; i < 4; i++) bf[i] = *(const short8*)&Bs[(rn + i * 16) * 40 + kl];
#pragma unroll
        for (int mi = 0; mi < 4; mi++)
#pragma unroll
            for (int ni = 0; ni < 4; ni++)
                acc[mi][ni] = __builtin_amdgcn_mfma_f32_16x16x32_bf16(af[mi], bf[ni], acc[mi][ni], 0, 0, 0);
    }

#pragma unroll
    for (int mi = 0; mi < 4; mi++)
#pragma unroll
        for (int ni = 0; ni < 4; ni++)
#pragma unroll
            for (int r = 0; r < 4; r++) {
                int row = row0 + wm * 64 + mi * 16 + ((lane >> 4) << 2) + r;
                int col = n0 + wn * 64 + ni * 16 + l15;
                dst[((size_t)row << 8) + col] = acc[mi][ni][r] + cbias[col];
            }
}

// ---------------------------------------------------------------------------
extern "C" void kernel_launch(void* const* d_in, const int* in_sizes, int n_in,
                              void* d_out, int out_size, void* d_ws, size_t ws_size,
                              hipStream_t stream)
{
    const float* q_data   = (const float*)d_in[0];
    const float* m_data   = (const float*)d_in[1];
    const float* bias     = (const float*)d_in[2];
    const float* nb       = (const float*)d_in[3];
    const float* query_w  = (const float*)d_in[4];
    const float* key_w    = (const float*)d_in[5];
    const float* value_w  = (const float*)d_in[6];
    const float* gating_w = (const float*)d_in[7];
    const float* gating_b = (const float*)d_in[8];
    const float* output_w = (const float*)d_in[9];
    const float* output_b = (const float*)d_in[10];

    const size_t NEED_A = 4ull * 33554432 + 524288 + 131072 + 1048576; // 135,921,664

    if (ws_size >= NEED_A) {
        // PATH A
        u16* ws   = (u16*)d_ws;
        u16* Kh   = ws;
        u16* Vh   = Kh + 16777216;
        u16* Qh   = Vh + 16777216;
        u16* GW   = Qh + 16777216;      // gate logits -> WA in place
        u16* wt   = GW + 16777216;      // 262144
        u16* WoT  = wt + 262144;        // 65536
        u16* nbbf = WoT + 65536;        // 524288
        u16* qbf  = (u16*)d_out;        // d_out scratch: dead until gemmout_a
        u16* mbf  = qbf + 16777216;

        prep_a<<<34560, 256, 0, stream>>>(q_data, m_data, nb,
                                          query_w, key_w, value_w, gating_w, output_w,
                                          qbf, mbf, nbbf, wt, WoT);
        proj_a<<<dim3(512, 8), 256, 0, stream>>>(mbf, qbf, wt, Kh, Vh, Qh, GW, gating_b);
        attn_a<<<2048, 256, 0, stream>>>(Qh, Kh, Vh, GW, bias, nbbf);
        gemmout_a<<<dim3(512, 2), 256, 0, stream>>>(GW, WoT, (float*)d_out, output_b);
    } else {
        // PATH B — round-4 proven pipeline
        u16* WAb = (u16*)d_ws;
        u16* wt  = (u16*)d_out;
        transpose_k<<<1024, 256, 0, stream>>>(query_w, key_w, value_w, gating_w, wt);
        fused_attn_k<<<2048, 256, 0, stream>>>(q_data, m_data, bias, nb, wt, gating_b, WAb);
        gemm_out_k<<<dim3(512, 2), 256, 0, stream>>>(WAb, output_w, (float*)d_out, output_b);
    }
}